// Round 8
// baseline (790.951 us; speedup 1.0000x reference)
//
#include <hip/hip_runtime.h>

#define TT 100
#define DD 100
#define DC 25      // DD/4
#define PP 10
#define BBATCH 256
#define OC 80

typedef float v2f __attribute__((ext_vector_type(2)));
typedef float v4f __attribute__((ext_vector_type(4)));
typedef short v8s __attribute__((ext_vector_type(8)));
typedef unsigned v4u __attribute__((ext_vector_type(4)));

static constexpr float FEPS = 1e-6f;
static constexpr float NEG_INF = -3.4e38f;

__device__ __forceinline__ float wsum(float v) {
#pragma unroll
  for (int m = 1; m < 64; m <<= 1) v += __shfl_xor(v, m, 64);
  return v;
}

__device__ __forceinline__ void wargmax(float& v, int& idx) {
#pragma unroll
  for (int m = 1; m < 64; m <<= 1) {
    float ov = __shfl_xor(v, m, 64);
    int   oi = __shfl_xor(idx, m, 64);
    if (ov > v || (ov == v && oi < idx)) { v = ov; idx = oi; }
  }
}

// RNE fp32 pair -> packed bf16x2, pure integer ALU (no structs/unions).
__device__ __forceinline__ unsigned pkbf(float lo, float hi) {
  unsigned a = __float_as_uint(lo);
  unsigned b = __float_as_uint(hi);
  a += 0x7FFFu + ((a >> 16) & 1u);
  b += 0x7FFFu + ((b >> 16) & 1u);
  return (a >> 16) | (b & 0xFFFF0000u);
}

__global__ __launch_bounds__(256, 2) void match_kernel(
    const float* __restrict__ s1, const float* __restrict__ s2,
    const float* __restrict__ w1, const float* __restrict__ w2,
    const float* __restrict__ w3, const float* __restrict__ w4,
    const float* __restrict__ w5, const float* __restrict__ w6,
    const float* __restrict__ w7, const float* __restrict__ w8,
    float* __restrict__ out)
{
  const int dir  = blockIdx.x & 1;
  const int b    = blockIdx.x >> 1;
  const int doff = dir * DD;
  const int tid  = threadIdx.x;
  const int lane = tid & 63;
  const int wv   = tid >> 6;

  const float* wfull = dir ? w2 : w1;
  const float* wmax  = dir ? w4 : w3;
  const float* wmean = dir ? w6 : w5;
  const float* watt2 = dir ? w8 : w7;   // fwd: max-att (w7); bwd: mean-att (w8)

  // s2 in d-chunked layout: d = 4c+k. j-stride = 16B (b128-able, conflict-free
  // lane-over-j); chunk stride = 101*4 = 404 dwords == 20 mod 32.
  __shared__ __align__(16) float S2V[DC][TT + 1][4];
  __shared__ __align__(16) float W2SQ[PP][DD];
  __shared__ float N2PI[TT];
  __shared__ float N2WI[TT][11];        // padded: (11j+p)%32 -> 2-way free
  __shared__ __align__(16) float S1R[16][DD];
  __shared__ __align__(16) float CROW[16][DD];
  __shared__ float N1PI[16];
  __shared__ float N1WI[16][PP];
  __shared__ int   ARGJ[16];

  // ---- Phase 1: load s2 tile (d-chunked) + maxpool w^2 ----
  for (int idx = tid; idx < TT * DD; idx += 256) {
    int j = idx / DD, d = idx - j * DD;
    S2V[d >> 2][j][d & 3] = s2[(j * BBATCH + b) * (2 * DD) + doff + d];
  }
  for (int idx = tid; idx < PP * DD; idx += 256) {
    float v = wmax[idx];
    W2SQ[idx / DD][idx - (idx / DD) * DD] = v * v;
  }
  __syncthreads();

  // ---- Phase 2: s2 norms (plain exact-ish + weighted rsqrt), float4 reads ----
  for (int task = tid; task < TT + TT * PP; task += 256) {
    if (task < TT) {
      int j = task;
      float a = 0.f;
      for (int c = 0; c < DC; ++c) {
        v4f f = *(const v4f*)&S2V[c][j][0];
#pragma unroll
        for (int k = 0; k < 4; ++k) a = fmaf(f[k], f[k], a);
      }
      N2PI[j] = 1.0f / sqrtf(fmaxf(a, FEPS));   // feeds argmax-sensitive cos
    } else {
      int q = task - TT; int j = q / PP, p = q - j * PP;
      float a = 0.f;
      for (int c = 0; c < DC; ++c) {
        v4f f = *(const v4f*)&S2V[c][j][0];
        v4f w = *(const v4f*)&W2SQ[p][4 * c];
#pragma unroll
        for (int k = 0; k < 4; ++k) a = fmaf(f[k] * f[k], w[k], a);
      }
      N2WI[j][p] = rsqrtf(fmaxf(a, FEPS));
    }
  }
  __syncthreads();

  const int  j0   = lane;
  const int  j1   = 64 + lane;
  const bool act1 = (j1 < TT);
  const int  j1c  = act1 ? j1 : (TT - 1);
  const bool actd = (64 + lane) < DD;
  const int  d1   = actd ? (64 + lane) : (DD - 1);
  const int  c0i  = lane >> 2, k0 = lane & 3;      // phase-D d0 = lane
  const int  c1i  = d1 >> 2,   k1 = d1 & 3;        // phase-D d1

  // ---- Phase 3: 7 block-iters x (4 waves x 4 rows) ----
  for (int t = 0; t < 7; ++t) {
    const int rbase = t * 16;
    for (int idx = tid; idx < 16 * DD; idx += 256) {
      int r = idx / DD, d = idx - r * DD;
      int row = rbase + r;
      S1R[r][d] = (row < TT) ? s1[(row * BBATCH + b) * (2 * DD) + doff + d] : 0.f;
    }
    __syncthreads();

    // cooperative s1 norms -> LDS
    for (int task = tid; task < 16 * 11; task += 256) {
      int rr = task / 11, q = task - rr * 11;
      if (q == 0) {
        float a = 0.f;
        for (int c = 0; c < DC; ++c) {
          v4f f = *(const v4f*)&S1R[rr][4 * c];
#pragma unroll
          for (int k = 0; k < 4; ++k) a = fmaf(f[k], f[k], a);
        }
        N1PI[rr] = 1.0f / sqrtf(fmaxf(a, FEPS));
      } else {
        int p = q - 1;
        float a = 0.f;
        for (int c = 0; c < DC; ++c) {
          v4f f = *(const v4f*)&S1R[rr][4 * c];
          v4f w = *(const v4f*)&W2SQ[p][4 * c];
#pragma unroll
          for (int k = 0; k < 4; ++k) a = fmaf(f[k] * f[k], w[k], a);
        }
        N1WI[rr][p] = rsqrtf(fmaxf(a, FEPS));
      }
    }
    __syncthreads();

    const int g = t * 4 + wv;
    const int i0 = g * 4;
    const int sl = wv * 4;
    const bool active = (g < 25);

    float rs[4] = {0, 0, 0, 0};
    v2f attp[4] = {{0, 0}, {0, 0}, {0, 0}, {0, 0}};

    // ---- Phase B: packed (j0,j1) plain dot pass, b128 LDS reads ----
    if (active) {
      v2f dotp[4] = {{0, 0}, {0, 0}, {0, 0}, {0, 0}};

      for (int c = 0; c < DC; ++c) {
        v4f s2a4 = *(const v4f*)&S2V[c][j0][0];
        v4f s2b4 = *(const v4f*)&S2V[c][j1c][0];
        v4f s1v[4];
#pragma unroll
        for (int r = 0; r < 4; ++r) s1v[r] = *(const v4f*)&S1R[sl + r][4 * c];
#pragma unroll
        for (int k = 0; k < 4; ++k) {
          v2f s2ab; s2ab.x = s2a4[k]; s2ab.y = s2b4[k];
#pragma unroll
          for (int r = 0; r < 4; ++r) {
            v2f s1xx; s1xx.x = s1v[r][k]; s1xx.y = s1v[r][k];
            dotp[r] += s1xx * s2ab;   // v_pk ops, scalar-identical rounding
          }
        }
      }

      // ---- Phase C: cos rows, rowsum, argmax ----
#pragma unroll
      for (int r = 0; r < 4; ++r) {
        float n1pi_r = N1PI[sl + r];
        float c0 = dotp[r].x * (n1pi_r * N2PI[j0]);
        float c1 = dotp[r].y * (n1pi_r * N2PI[j1c]);
        CROW[sl + r][j0] = c0;
        if (act1) CROW[sl + r][j1] = c1;
        rs[r] = wsum(c0 + (act1 ? c1 : 0.f));

        float mv = c0; int mi = j0;
        if (act1 && (c1 > mv)) { mv = c1; mi = j1; }
        wargmax(mv, mi);
        if (lane == 0) ARGJ[sl + r] = mi;
      }
    }

    // ---- MFMA maxpool section (ALL waves; wave wv owns p in {wv,wv+4,wv+8}).
    // Fed entirely from LDS (S1R, S2V, W2SQ, N2WI, N1WI): no global loads in
    // the body. Constant-trip unroll; clamped duplicate p for waves 2,3.
    {
      const int col = lane & 15;
      const int qd  = lane >> 4;
      const v4f vz = {0.f, 0.f, 0.f, 0.f};

      v4u afr[3][4];
      float rmax[3][4];
#pragma unroll
      for (int pi = 0; pi < 3; ++pi) {
        const int p = (wv + 4 * pi < PP) ? (wv + 4 * pi) : (PP - 1);
#pragma unroll
        for (int kc = 0; kc < 4; ++kc) {
          v4f x0, x1, w0, w1;
          if (kc < 3) {
            int d0 = kc * 32 + qd * 8;
            x0 = *(const v4f*)&S1R[col][d0];
            x1 = *(const v4f*)&S1R[col][d0 + 4];
            w0 = *(const v4f*)&W2SQ[p][d0];
            w1 = *(const v4f*)&W2SQ[p][d0 + 4];
          } else {               // d0 = 96 + qd*8: only qd==0 low half valid
            bool ok = (qd == 0);
            x0 = ok ? *(const v4f*)&S1R[col][96] : vz;
            w0 = ok ? *(const v4f*)&W2SQ[p][96] : vz;
            x1 = vz; w1 = vz;
          }
          v4u f;                 // A = bf16(s1 * w^2) — W2SQ is pre-squared
          f.x = pkbf(x0[0] * w0[0], x0[1] * w0[1]);
          f.y = pkbf(x0[2] * w0[2], x0[3] * w0[3]);
          f.z = pkbf(x1[0] * w1[0], x1[1] * w1[1]);
          f.w = pkbf(x1[2] * w1[2], x1[3] * w1[3]);
          afr[pi][kc] = f;
        }
#pragma unroll
        for (int r = 0; r < 4; ++r) rmax[pi][r] = NEG_INF;
      }

      for (int jt = 0; jt < 7; ++jt) {
        int jr = jt * 16 + col;
        int jc = (jr < TT) ? jr : (TT - 1);
        v4u bfr[4];                       // B = bf16(s2), row = jr
#pragma unroll
        for (int kc = 0; kc < 4; ++kc) {
          int ch = kc * 8 + qd * 2;
          int ch0 = (ch     <= 24) ? ch     : 24;
          int ch1 = (ch + 1 <= 24) ? ch + 1 : 24;
          v4f y0 = (ch     <= 24) ? *(const v4f*)&S2V[ch0][jc][0] : vz;
          v4f y1 = (ch + 1 <= 24) ? *(const v4f*)&S2V[ch1][jc][0] : vz;
          v4u f;
          f.x = pkbf(y0[0], y0[1]); f.y = pkbf(y0[2], y0[3]);
          f.z = pkbf(y1[0], y1[1]); f.w = pkbf(y1[2], y1[3]);
          bfr[kc] = f;
        }
#pragma unroll
        for (int pi = 0; pi < 3; ++pi) {
          const int p = (wv + 4 * pi < PP) ? (wv + 4 * pi) : (PP - 1);
          v4f acc = {0.f, 0.f, 0.f, 0.f};
#pragma unroll
          for (int kc = 0; kc < 4; ++kc)
            acc = __builtin_amdgcn_mfma_f32_16x16x32_bf16(
                __builtin_bit_cast(v8s, afr[pi][kc]),
                __builtin_bit_cast(v8s, bfr[kc]), acc, 0, 0, 0);
          if (jr < TT) {                 // C col = lane&15 -> j (m89-verified)
            float n2 = N2WI[jr][p];
#pragma unroll
            for (int r = 0; r < 4; ++r)
              rmax[pi][r] = fmaxf(rmax[pi][r], acc[r] * n2);
          }
        }
      }
#pragma unroll
      for (int pi = 0; pi < 3; ++pi) {
        const int p = wv + 4 * pi;
        if (p < PP) {                    // wave-uniform guard
#pragma unroll
          for (int m = 1; m < 16; m <<= 1)
#pragma unroll
            for (int r = 0; r < 4; ++r)
              rmax[pi][r] = fmaxf(rmax[pi][r], __shfl_xor(rmax[pi][r], m, 64));
          if (col == 0) {
#pragma unroll
            for (int r = 0; r < 4; ++r) {
              int lrow = qd * 4 + r;     // C row = quad*4+reg (m89-verified)
              int row = rbase + lrow;
              if (row < TT)
                out[(row * BBATCH + b) * OC + 20 + dir * PP + p] =
                    rmax[pi][r] * N1WI[lrow][p];
            }
          }
        }
      }
    }
    __syncthreads();  // cos rows + ARGJ visible block-wide

    // ---- Phase D: mean-att accumulation, packed (d0,d1) ----
    if (active) {
      for (int j = 0; j < TT; ++j) {
        v2f s2ab; s2ab.x = S2V[c0i][j][k0]; s2ab.y = S2V[c1i][j][k1];
#pragma unroll
        for (int r = 0; r < 4; ++r) {
          float cv = CROW[sl + r][j];
          v2f cc; cc.x = cv; cc.y = cv;
          attp[r] = __builtin_elementwise_fma(cc, s2ab, attp[r]);
        }
      }
    }
    __syncthreads();  // all cos reads done before overwrite

    if (active) {
#pragma unroll
      for (int r = 0; r < 4; ++r) {
        float inv = 1.0f / (rs[r] + FEPS);
        CROW[sl + r][lane] = attp[r].x * inv;
        if (actd) CROW[sl + r][64 + lane] = attp[r].y * inv;
      }
    }
    __syncthreads();  // att rows visible

    // ---- Phase E: epilogue: 120 tasks = 4 rows x {full, mean-att, att2} x 10 p
    if (active) {
      for (int tk = lane; tk < 120; tk += 64) {
        int r = tk / 30;
        int q = tk - r * 30;
        int set = q / PP;
        int p = q - set * PP;
        const float* wrow = (set == 0 ? wfull : (set == 1 ? wmean : watt2)) + p * DD;
        // reference quirk: s2.reshape(-1,D)[argmax] == s2f[0, argmax, :] (fwd only)
        const float* gat = s2 + ARGJ[sl + r] * (2 * DD);
        float num = 0.f, nx = 0.f, ny = 0.f;
        for (int c = 0; c < DC; ++c) {
          v4f x4 = *(const v4f*)&S1R[sl + r][4 * c];
          v4f y4;
          if (set == 0)                     y4 = *(const v4f*)&S2V[c][TT - 1][0];
          else if (set == 1 || dir == 1)    y4 = *(const v4f*)&CROW[sl + r][4 * c];
          else                              y4 = *(const v4f*)&gat[4 * c];
          v4f w4 = *(const v4f*)&wrow[4 * c];
#pragma unroll
          for (int k = 0; k < 4; ++k) {
            float w2v = w4[k] * w4[k];
            num = fmaf(x4[k] * y4[k], w2v, num);
            nx  = fmaf(x4[k] * x4[k], w2v, nx);
            ny  = fmaf(y4[k] * y4[k], w2v, ny);
          }
        }
        float cres = num * rsqrtf(fmaxf(nx, FEPS)) * rsqrtf(fmaxf(ny, FEPS));
        int ch = (set == 0 ? 0 : (set == 1 ? 40 : 60)) + dir * PP + p;
        out[((i0 + r) * BBATCH + b) * OC + ch] = cres;
      }
    }
    __syncthreads();  // before next-t staging overwrites S1R
  }
}

extern "C" void kernel_launch(void* const* d_in, const int* in_sizes, int n_in,
                              void* d_out, int out_size, void* d_ws, size_t ws_size,
                              hipStream_t stream) {
  const float* s1 = (const float*)d_in[0];
  const float* s2 = (const float*)d_in[1];
  match_kernel<<<dim3(512), dim3(256), 0, stream>>>(
      s1, s2,
      (const float*)d_in[2], (const float*)d_in[3],
      (const float*)d_in[4], (const float*)d_in[5],
      (const float*)d_in[6], (const float*)d_in[7],
      (const float*)d_in[8], (const float*)d_in[9],
      (float*)d_out);
}